// Round 1
// baseline (48.691 us; speedup 1.0000x reference)
//
#include <hip/hip_runtime.h>
#include <hip/hip_bf16.h>

namespace {

constexpr int kB = 2;
constexpr int kL = 2048;
constexpr int kD = 1024;
constexpr int kN = 16;
constexpr int kTPB = 256;
constexpr int kNDBLK = kD / kTPB;   // 4 blocks cover D
constexpr int kBD = kB * kD;        // 2048
constexpr int kBDN = kB * kD * kN;  // 32768
constexpr float kLog2e = 1.4426950408889634f;

__device__ __forceinline__ float fast_exp2(float v) {
  return __builtin_amdgcn_exp2f(v);
}

// ---------------- Phase 1: per-chunk aggregates ----------------
// Thread owns one (b, d); runs its chunk with state 0; writes per-n
// chunk a-product and chunk-local final state.
// Workspace layout: W[c][n][b*kD + d]  (coalesced in d for phases 1/3,
// coalesced in the flat j index for phase 2).
template <int C>
__global__ __launch_bounds__(kTPB) void ssm_phase1(
    const float* __restrict__ x, const float* __restrict__ dt,
    const float* __restrict__ Bin, const float* __restrict__ Alog,
    float* __restrict__ WA, float* __restrict__ WS) {
  constexpr int LC = kL / C;
  const int bid = blockIdx.x;
  const int c = bid % C;
  const int r = bid / C;
  const int dblk = r % kNDBLK;
  const int b = r / kNDBLK;
  const int d = dblk * kTPB + threadIdx.x;

  float An[kN];
  const float* al = Alog + d * kN;
#pragma unroll
  for (int n = 0; n < kN; ++n) An[n] = -__expf(al[n]) * kLog2e;

  float s[kN], ap[kN];
#pragma unroll
  for (int n = 0; n < kN; ++n) { s[n] = 0.f; ap[n] = 1.f; }

  const int t0 = c * LC;
  const float* xp  = x  + ((size_t)b * kL + t0) * kD + d;
  const float* dtp = dt + ((size_t)b * kL + t0) * kD + d;
  const float* bp  = Bin + ((size_t)b * kL + t0) * kN;

#pragma unroll 4
  for (int tt = 0; tt < LC; ++tt) {
    const float dtv = dtp[(size_t)tt * kD];
    const float xv  = xp[(size_t)tt * kD];
    const float dtx = dtv * xv;
#pragma unroll
    for (int n = 0; n < kN; ++n) {
      const float a = fast_exp2(dtv * An[n]);
      s[n] = fmaf(a, s[n], dtx * bp[tt * kN + n]);
      ap[n] *= a;
    }
  }

  const size_t base = (size_t)c * kBDN + (size_t)b * kD + d;
#pragma unroll
  for (int n = 0; n < kN; ++n) {
    WA[base + (size_t)n * kBD] = ap[n];
    WS[base + (size_t)n * kBD] = s[n];
  }
}

// ---------------- Phase 2: scan across chunks ----------------
template <int C>
__global__ __launch_bounds__(256) void ssm_phase2(
    const float* __restrict__ WA, const float* __restrict__ WS,
    float* __restrict__ WI) {
  const int i = blockIdx.x * 256 + threadIdx.x;  // < kBDN
  float carry = 0.f;
  for (int c = 0; c < C; ++c) {
    const size_t idx = (size_t)c * kBDN + i;
    const float a  = WA[idx];
    const float sf = WS[idx];
    WI[idx] = carry;               // true initial state of chunk c
    carry = fmaf(a, carry, sf);    // true final state of chunk c
  }
}

// ---------------- Phase 3: re-run with true init, fused epilogue ----------------
template <int C>
__global__ __launch_bounds__(kTPB) void ssm_phase3(
    const float* __restrict__ x, const float* __restrict__ dt,
    const float* __restrict__ Bin, const float* __restrict__ Cin,
    const float* __restrict__ Alog, const float* __restrict__ Dp,
    const float* __restrict__ WI, float* __restrict__ y) {
  constexpr int LC = kL / C;
  const int bid = blockIdx.x;
  const int c = bid % C;
  const int r = bid / C;
  const int dblk = r % kNDBLK;
  const int b = r / kNDBLK;
  const int d = dblk * kTPB + threadIdx.x;

  float An[kN];
  const float* al = Alog + d * kN;
#pragma unroll
  for (int n = 0; n < kN; ++n) An[n] = -__expf(al[n]) * kLog2e;

  float s[kN];
  const size_t base = (size_t)c * kBDN + (size_t)b * kD + d;
#pragma unroll
  for (int n = 0; n < kN; ++n) s[n] = WI[base + (size_t)n * kBD];

  const float Dv = Dp[d];

  const int t0 = c * LC;
  const float* xp  = x  + ((size_t)b * kL + t0) * kD + d;
  const float* dtp = dt + ((size_t)b * kL + t0) * kD + d;
  const float* bp  = Bin + ((size_t)b * kL + t0) * kN;
  const float* cp  = Cin + ((size_t)b * kL + t0) * kN;
  float* yp = y + ((size_t)b * kL + t0) * kD + d;

#pragma unroll 4
  for (int tt = 0; tt < LC; ++tt) {
    const float dtv = dtp[(size_t)tt * kD];
    const float xv  = xp[(size_t)tt * kD];
    const float dtx = dtv * xv;
    float acc = 0.f;
#pragma unroll
    for (int n = 0; n < kN; ++n) {
      const float a = fast_exp2(dtv * An[n]);
      s[n] = fmaf(a, s[n], dtx * bp[tt * kN + n]);
      acc = fmaf(s[n], cp[tt * kN + n], acc);
    }
    yp[(size_t)tt * kD] = fmaf(xv, Dv, acc);
  }
}

// ---------------- Fallback: fully sequential (no workspace) ----------------
__global__ __launch_bounds__(256) void ssm_seq(
    const float* __restrict__ x, const float* __restrict__ dt,
    const float* __restrict__ Bin, const float* __restrict__ Cin,
    const float* __restrict__ Alog, const float* __restrict__ Dp,
    float* __restrict__ y) {
  const int gid = blockIdx.x * 256 + threadIdx.x;  // over kB*kD
  if (gid >= kB * kD) return;
  const int b = gid / kD;
  const int d = gid % kD;

  float An[kN];
  const float* al = Alog + d * kN;
#pragma unroll
  for (int n = 0; n < kN; ++n) An[n] = -__expf(al[n]) * kLog2e;

  float s[kN];
#pragma unroll
  for (int n = 0; n < kN; ++n) s[n] = 0.f;
  const float Dv = Dp[d];

  const float* xp  = x  + (size_t)b * kL * kD + d;
  const float* dtp = dt + (size_t)b * kL * kD + d;
  const float* bp  = Bin + (size_t)b * kL * kN;
  const float* cp  = Cin + (size_t)b * kL * kN;
  float* yp = y + (size_t)b * kL * kD + d;

  for (int t = 0; t < kL; ++t) {
    const float dtv = dtp[(size_t)t * kD];
    const float xv  = xp[(size_t)t * kD];
    const float dtx = dtv * xv;
    float acc = 0.f;
#pragma unroll
    for (int n = 0; n < kN; ++n) {
      const float a = fast_exp2(dtv * An[n]);
      s[n] = fmaf(a, s[n], dtx * bp[t * kN + n]);
      acc = fmaf(s[n], cp[t * kN + n], acc);
    }
    yp[(size_t)t * kD] = fmaf(xv, Dv, acc);
  }
}

template <int C>
void launch_chunked(const float* x, const float* dtp, const float* Bin,
                    const float* Cin, const float* Alog, const float* Dp,
                    float* y, float* ws, hipStream_t stream) {
  float* WA = ws;
  float* WS = WA + (size_t)C * kBDN;
  float* WI = WS + (size_t)C * kBDN;
  const int g1 = C * kB * kNDBLK;
  ssm_phase1<C><<<g1, kTPB, 0, stream>>>(x, dtp, Bin, Alog, WA, WS);
  ssm_phase2<C><<<kBDN / 256, 256, 0, stream>>>(WA, WS, WI);
  ssm_phase3<C><<<g1, kTPB, 0, stream>>>(x, dtp, Bin, Cin, Alog, Dp, WI, y);
}

}  // namespace

extern "C" void kernel_launch(void* const* d_in, const int* in_sizes, int n_in,
                              void* d_out, int out_size, void* d_ws, size_t ws_size,
                              hipStream_t stream) {
  const float* x    = (const float*)d_in[0];
  const float* dtp  = (const float*)d_in[1];
  const float* Bin  = (const float*)d_in[2];
  const float* Cin  = (const float*)d_in[3];
  const float* Alog = (const float*)d_in[4];
  const float* Dp   = (const float*)d_in[5];
  float* y = (float*)d_out;
  float* ws = (float*)d_ws;

  auto need = [](int C) { return (size_t)3 * C * kBDN * sizeof(float); };

  if (ws_size >= need(64)) {
    launch_chunked<64>(x, dtp, Bin, Cin, Alog, Dp, y, ws, stream);
  } else if (ws_size >= need(16)) {
    launch_chunked<16>(x, dtp, Bin, Cin, Alog, Dp, y, ws, stream);
  } else if (ws_size >= need(4)) {
    launch_chunked<4>(x, dtp, Bin, Cin, Alog, Dp, y, ws, stream);
  } else {
    ssm_seq<<<(kB * kD + 255) / 256, 256, 0, stream>>>(x, dtp, Bin, Cin, Alog,
                                                       Dp, y);
  }
}

// Round 2
// 41.547 us; speedup vs baseline: 1.1719x; 1.1719x over previous
//
#include <hip/hip_runtime.h>
#include <hip/hip_bf16.h>

namespace {

constexpr int kB = 2;
constexpr int kL = 2048;
constexpr int kD = 1024;
constexpr int kN = 16;
constexpr int kTPB = 256;
constexpr int kNDBLK = kD / kTPB;   // 4 blocks cover D
constexpr int kBD = kB * kD;        // 2048
constexpr int kBDN = kBD * kN;      // 32768
constexpr float kLog2e = 1.4426950408889634f;

__device__ __forceinline__ float ex2(float v) {
  return __builtin_amdgcn_exp2f(v);
}

// a[n] = e1^(n+1), log-depth (4 squares + 11 muls, depth ~5)
__device__ __forceinline__ void build_pows(float e1, float* a) {
  const float p2 = e1 * e1;
  const float p4 = p2 * p2;
  const float p8 = p4 * p4;
  a[0] = e1;      a[1] = p2;      a[2] = p2 * e1; a[3] = p4;
  a[4] = p4 * e1; a[5] = p4 * p2; a[6] = p4 * a[2]; a[7] = p8;
  a[8] = p8 * e1; a[9] = p8 * p2; a[10] = p8 * a[2]; a[11] = p8 * p4;
  a[12] = p8 * a[4]; a[13] = p8 * a[5]; a[14] = p8 * a[6]; a[15] = p8 * p8;
}

// ---------------- Phase 1: per-chunk local scan ----------------
// Stores chunk-local final states WS[c][n][bd] and chunk dt-sum SDT[c][bd]
// (chunk a-product is exp(An * sdt), computed later — saves 16 muls/step
// and 16 floats/thread of traffic).
template <int C>
__global__ __launch_bounds__(kTPB) void ssm_phase1(
    const float* __restrict__ x, const float* __restrict__ dt,
    const float* __restrict__ Bin, const float* __restrict__ Alog,
    float* __restrict__ WS, float* __restrict__ SDT) {
  constexpr int LC = kL / C;
  const int bid = blockIdx.x;
  const int c = bid % C;
  const int r = bid / C;
  const int dblk = r % kNDBLK;
  const int b = r / kNDBLK;
  const int d = dblk * kTPB + threadIdx.x;

  float AnL[kN];
  const float* al = Alog + d * kN;
#pragma unroll
  for (int n = 0; n < kN; ++n) AnL[n] = -__expf(al[n]) * kLog2e;
  bool fast = true;
#pragma unroll
  for (int n = 1; n < kN; ++n)
    fast = fast && (fabsf(AnL[n] - (float)(n + 1) * AnL[0]) <=
                    1e-4f * fabsf(AnL[n]));

  float s[kN];
#pragma unroll
  for (int n = 0; n < kN; ++n) s[n] = 0.f;
  float sdt = 0.f;

  const int t0 = c * LC;
  const float* xp = x + ((size_t)b * kL + t0) * kD + d;
  const float* dp = dt + ((size_t)b * kL + t0) * kD + d;
  const float* bp = Bin + ((size_t)b * kL + t0) * kN;

  if (fast) {
    const float A0 = AnL[0];
#pragma unroll 4
    for (int tt = 0; tt < LC; ++tt) {
      const float dtv = dp[(size_t)tt * kD];
      const float xv = xp[(size_t)tt * kD];
      sdt += dtv;
      const float dtx = dtv * xv;
      float a[kN];
      build_pows(ex2(dtv * A0), a);
#pragma unroll
      for (int n = 0; n < kN; ++n)
        s[n] = fmaf(a[n], s[n], dtx * bp[tt * kN + n]);
    }
  } else {
#pragma unroll 2
    for (int tt = 0; tt < LC; ++tt) {
      const float dtv = dp[(size_t)tt * kD];
      const float xv = xp[(size_t)tt * kD];
      sdt += dtv;
      const float dtx = dtv * xv;
#pragma unroll
      for (int n = 0; n < kN; ++n) {
        const float a = ex2(dtv * AnL[n]);
        s[n] = fmaf(a, s[n], dtx * bp[tt * kN + n]);
      }
    }
  }

  const size_t bd = (size_t)b * kD + d;
#pragma unroll
  for (int n = 0; n < kN; ++n)
    WS[(size_t)c * kBDN + (size_t)n * kBD + bd] = s[n];
  SDT[(size_t)c * kBD + bd] = sdt;
}

// ---------------- Phase 2: scan across chunk aggregates ----------------
template <int C>
__global__ __launch_bounds__(256) void ssm_phase2(
    const float* __restrict__ WS, const float* __restrict__ SDT,
    const float* __restrict__ Alog, float* __restrict__ WI) {
  const int i = blockIdx.x * 256 + threadIdx.x;  // < kBDN, i = n*kBD + bd
  const int n = i >> 11;                          // / kBD
  const int bd = i & (kBD - 1);
  const int d = bd & (kD - 1);
  const float An = -__expf(Alog[d * kN + n]) * kLog2e;
  float carry = 0.f;
  for (int c = 0; c < C; ++c) {
    const size_t idx = (size_t)c * kBDN + i;
    const float a = ex2(An * SDT[(size_t)c * kBD + bd]);
    WI[idx] = carry;              // true initial state of chunk c
    carry = fmaf(a, carry, WS[idx]);
  }
}

// ---------------- Phase 3: re-run with true init, fused epilogue ----------------
template <int C>
__global__ __launch_bounds__(kTPB) void ssm_phase3(
    const float* __restrict__ x, const float* __restrict__ dt,
    const float* __restrict__ Bin, const float* __restrict__ Cin,
    const float* __restrict__ Alog, const float* __restrict__ Dp,
    const float* __restrict__ WI, float* __restrict__ y) {
  constexpr int LC = kL / C;
  const int bid = blockIdx.x;
  const int c = bid % C;
  const int r = bid / C;
  const int dblk = r % kNDBLK;
  const int b = r / kNDBLK;
  const int d = dblk * kTPB + threadIdx.x;

  float AnL[kN];
  const float* al = Alog + d * kN;
#pragma unroll
  for (int n = 0; n < kN; ++n) AnL[n] = -__expf(al[n]) * kLog2e;
  bool fast = true;
#pragma unroll
  for (int n = 1; n < kN; ++n)
    fast = fast && (fabsf(AnL[n] - (float)(n + 1) * AnL[0]) <=
                    1e-4f * fabsf(AnL[n]));

  float s[kN];
  const size_t bd = (size_t)b * kD + d;
#pragma unroll
  for (int n = 0; n < kN; ++n)
    s[n] = WI[(size_t)c * kBDN + (size_t)n * kBD + bd];

  const float Dv = Dp[d];

  const int t0 = c * LC;
  const float* xp = x + ((size_t)b * kL + t0) * kD + d;
  const float* dp = dt + ((size_t)b * kL + t0) * kD + d;
  const float* bp = Bin + ((size_t)b * kL + t0) * kN;
  const float* cp = Cin + ((size_t)b * kL + t0) * kN;
  float* yp = y + ((size_t)b * kL + t0) * kD + d;

  if (fast) {
    const float A0 = AnL[0];
#pragma unroll 4
    for (int tt = 0; tt < LC; ++tt) {
      const float dtv = dp[(size_t)tt * kD];
      const float xv = xp[(size_t)tt * kD];
      const float dtx = dtv * xv;
      float a[kN];
      build_pows(ex2(dtv * A0), a);
      float acc = 0.f;
#pragma unroll
      for (int n = 0; n < kN; ++n) {
        s[n] = fmaf(a[n], s[n], dtx * bp[tt * kN + n]);
        acc = fmaf(s[n], cp[tt * kN + n], acc);
      }
      yp[(size_t)tt * kD] = fmaf(xv, Dv, acc);
    }
  } else {
#pragma unroll 2
    for (int tt = 0; tt < LC; ++tt) {
      const float dtv = dp[(size_t)tt * kD];
      const float xv = xp[(size_t)tt * kD];
      const float dtx = dtv * xv;
      float acc = 0.f;
#pragma unroll
      for (int n = 0; n < kN; ++n) {
        const float a = ex2(dtv * AnL[n]);
        s[n] = fmaf(a, s[n], dtx * bp[tt * kN + n]);
        acc = fmaf(s[n], cp[tt * kN + n], acc);
      }
      yp[(size_t)tt * kD] = fmaf(xv, Dv, acc);
    }
  }
}

// ---------------- Fallback: fully sequential (no workspace) ----------------
__global__ __launch_bounds__(256) void ssm_seq(
    const float* __restrict__ x, const float* __restrict__ dt,
    const float* __restrict__ Bin, const float* __restrict__ Cin,
    const float* __restrict__ Alog, const float* __restrict__ Dp,
    float* __restrict__ y) {
  const int gid = blockIdx.x * 256 + threadIdx.x;  // over kB*kD
  if (gid >= kB * kD) return;
  const int b = gid / kD;
  const int d = gid % kD;

  float AnL[kN];
  const float* al = Alog + d * kN;
#pragma unroll
  for (int n = 0; n < kN; ++n) AnL[n] = -__expf(al[n]) * kLog2e;

  float s[kN];
#pragma unroll
  for (int n = 0; n < kN; ++n) s[n] = 0.f;
  const float Dv = Dp[d];

  const float* xp = x + (size_t)b * kL * kD + d;
  const float* dp = dt + (size_t)b * kL * kD + d;
  const float* bp = Bin + (size_t)b * kL * kN;
  const float* cp = Cin + (size_t)b * kL * kN;
  float* yp = y + (size_t)b * kL * kD + d;

  for (int t = 0; t < kL; ++t) {
    const float dtv = dp[(size_t)t * kD];
    const float xv = xp[(size_t)t * kD];
    const float dtx = dtv * xv;
    float acc = 0.f;
#pragma unroll
    for (int n = 0; n < kN; ++n) {
      const float a = ex2(dtv * AnL[n]);
      s[n] = fmaf(a, s[n], dtx * bp[t * kN + n]);
      acc = fmaf(s[n], cp[t * kN + n], acc);
    }
    yp[(size_t)t * kD] = fmaf(xv, Dv, acc);
  }
}

template <int C>
void launch_chunked(const float* x, const float* dtp, const float* Bin,
                    const float* Cin, const float* Alog, const float* Dp,
                    float* y, float* ws, hipStream_t stream) {
  float* WS = ws;                                  // C * kBDN
  float* SDT = WS + (size_t)C * kBDN;              // C * kBD
  float* WI = SDT + (size_t)C * kBD;               // C * kBDN
  const int g = C * kB * kNDBLK;
  ssm_phase1<C><<<g, kTPB, 0, stream>>>(x, dtp, Bin, Alog, WS, SDT);
  ssm_phase2<C><<<kBDN / 256, 256, 0, stream>>>(WS, SDT, Alog, WI);
  ssm_phase3<C><<<g, kTPB, 0, stream>>>(x, dtp, Bin, Cin, Alog, Dp, WI, y);
}

}  // namespace

extern "C" void kernel_launch(void* const* d_in, const int* in_sizes, int n_in,
                              void* d_out, int out_size, void* d_ws, size_t ws_size,
                              hipStream_t stream) {
  const float* x    = (const float*)d_in[0];
  const float* dtp  = (const float*)d_in[1];
  const float* Bin  = (const float*)d_in[2];
  const float* Cin  = (const float*)d_in[3];
  const float* Alog = (const float*)d_in[4];
  const float* Dp   = (const float*)d_in[5];
  float* y = (float*)d_out;
  float* ws = (float*)d_ws;

  auto need = [](int C) {
    return (size_t)(2 * C * kBDN + C * kBD) * sizeof(float);
  };

  if (ws_size >= need(128)) {
    launch_chunked<128>(x, dtp, Bin, Cin, Alog, Dp, y, ws, stream);
  } else if (ws_size >= need(64)) {
    launch_chunked<64>(x, dtp, Bin, Cin, Alog, Dp, y, ws, stream);
  } else if (ws_size >= need(16)) {
    launch_chunked<16>(x, dtp, Bin, Cin, Alog, Dp, y, ws, stream);
  } else {
    ssm_seq<<<(kB * kD + 255) / 256, 256, 0, stream>>>(x, dtp, Bin, Cin, Alog,
                                                       Dp, y);
  }
}